// Round 6
// baseline (595.908 us; speedup 1.0000x reference)
//
#include <hip/hip_runtime.h>

#define T_STEPS 512
#define HID 64

typedef short bf16x8 __attribute__((ext_vector_type(8)));
typedef float f32x4 __attribute__((ext_vector_type(4)));

__device__ __forceinline__ float sigm(float x) {
  return __builtin_amdgcn_rcpf(1.f + __expf(-x));
}
__device__ __forceinline__ float tanh_fast(float x) {
  return 1.f - 2.f * __builtin_amdgcn_rcpf(__expf(2.f * x) + 1.f);
}

// split fp32 -> bf16 hi (chop) + bf16 lo (chop of exact residual)
__device__ __forceinline__ void split1(float v, short* hi, short* lo) {
  unsigned u = __float_as_uint(v);
  float r = v - __uint_as_float(u & 0xffff0000u);   // exact in fp32
  *hi = (short)(u >> 16);
  *lo = (short)(__float_as_uint(r) >> 16);
}

__device__ __forceinline__ void split8(const float* __restrict__ p, bf16x8& hi, bf16x8& lo) {
  float v[8];
  *(float4*)&v[0] = *(const float4*)p;
  *(float4*)&v[4] = *(const float4*)(p + 4);
  #pragma unroll
  for (int i = 0; i < 8; ++i) {
    unsigned u = __float_as_uint(v[i]);
    float r = v[i] - __uint_as_float(u & 0xffff0000u);
    hi[i] = (short)(u >> 16);
    lo[i] = (short)(__float_as_uint(r) >> 16);
  }
}

#define MM(acc, A, B) acc = __builtin_amdgcn_mfma_f32_16x16x32_bf16((A), (B), (acc), 0, 0, 0)

// K-concat 6-chunk accumulation: Wh*vh (2 chunks) + Wh*vl + Wl*vh
#define GATE6(acc, IH0, IH1, IL0, IL1, NM) do { \
    MM(acc, IH0, NM##h0); MM(acc, IH1, NM##h1); \
    MM(acc, IL0, NM##h0); MM(acc, IL1, NM##h1); \
    MM(acc, IH0, NM##l0); MM(acc, IH1, NM##l1); } while (0)

#define WFRAG(NM, Wp, goff) \
  bf16x8 NM##h0, NM##l0, NM##h1, NM##l1; \
  split8((Wp) + (goff) * (64 * HID) + wrowoff, NM##h0, NM##l0); \
  split8((Wp) + (goff) * (64 * HID) + wrowoff + 32, NM##h1, NM##l1)

// Grid 256 x WG 512 (8 waves, 2/SIMD). Waves 0-3: layer 0 (j-slice = wave&3);
// waves 4-7: layer 1, skewed one step (computes hB(i-1) at iteration i).
// Each wave holds only its layer's weight B-fragments (96 regs) -> 2 waves/SIMD fit.
// LDS matrices XOR-swizzled as in R5 (verified conflict-free); all double-buffered;
// ONE barrier per iteration.
__global__ __launch_bounds__(512, 2) void gru_mfma(
    const float* __restrict__ x,
    const float* __restrict__ Wih0, const float* __restrict__ Whh0,
    const float* __restrict__ bih0, const float* __restrict__ bhh0,
    const float* __restrict__ Wih1, const float* __restrict__ Whh1,
    const float* __restrict__ bih1, const float* __restrict__ bhh1,
    const float* __restrict__ W1, const float* __restrict__ b1,
    const float* __restrict__ W2, const float* __restrict__ b2,
    float* __restrict__ out)
{
  const int tid   = threadIdx.x;
  const int lane  = tid & 63;
  const int wv8   = tid >> 6;       // 0..7
  const int layer = wv8 >> 2;       // 0 or 1
  const int ws    = wv8 & 3;        // j-slice within layer
  const int nloc  = lane & 15;
  const int quad  = lane >> 4;
  const int b0    = blockIdx.x << 2;

  __shared__ __align__(16) short xsH[2][1024], xsL[2][1024];
  __shared__ __align__(16) short hAH[2][1024], hAL[2][1024];
  __shared__ __align__(16) short hBH[2][1024], hBL[2][1024];
  __shared__ float hfin[256];
  __shared__ float msf[128];

  // ---- this wave's layer weights only ----
  const float* Wi = layer ? Wih1 : Wih0;
  const float* Wh = layer ? Whh1 : Whh0;
  const float* bi = layer ? bih1 : bih0;
  const float* bh = layer ? bhh1 : bhh0;

  const int wrowoff = (16 * ws + nloc) * HID + 8 * quad;
  WFRAG(wir, Wi, 0); WFRAG(wiz, Wi, 1); WFRAG(win, Wi, 2);
  WFRAG(whr, Wh, 0); WFRAG(whz, Wh, 1); WFRAG(whn, Wh, 2);

  const int jg = 16 * ws + nloc;
  const float b_r = bi[jg] + bh[jg];
  const float b_z = bi[jg + 64] + bh[jg + 64];
  const float b_i = bi[jg + 128];
  const float b_h = bh[jg + 128];

  // loop-invariant LDS indices (shorts) — layout verified in R5
  const int ra0 = nloc * 64 + (((quad    ) ^ (nloc & 7)) << 3);
  const int ra1 = nloc * 64 + (((quad + 4) ^ (nloc & 7)) << 3);
  const int hwr = quad * 256 + (((jg >> 3) ^ ((quad & 1) << 2)) << 3) + (jg & 7);

  // x stager: L0 threads (tid<256), batch = wv8 (0..3), channel = lane
  const float* xptr = x + ((size_t)(b0 + (wv8 & 3)) * HID + lane) * T_STEPS;
  const int xwr = (wv8 & 3) * 256 + (((lane >> 3) ^ ((wv8 & 1) << 2)) << 3) + (lane & 7);

  for (int i = tid; i < 2048; i += 512) {
    (&xsH[0][0])[i] = 0; (&xsL[0][0])[i] = 0;
    (&hAH[0][0])[i] = 0; (&hAL[0][0])[i] = 0;
    (&hBH[0][0])[i] = 0; (&hBL[0][0])[i] = 0;
  }
  __syncthreads();
  if (tid < 256) {
    short h, l; split1(xptr[0], &h, &l);
    xsH[0][xwr] = h; xsL[0][xwr] = l;
  }
  __syncthreads();

  float hp = 0.f;       // lane's h[batch=quad][j=jg] for its layer
  float xnext = 0.f;

  #pragma unroll 1
  for (int i = 0; i <= T_STEPS; ++i) {
    const int pa = i & 1;
    const int pb = pa ^ 1;
    // input: L0 reads xs(i) from xs[pa]; L1 reads hA(i-1) from hA[pb]
    const short* inH = layer ? hAH[pb] : xsH[pa];
    const short* inL = layer ? hAL[pb] : xsL[pa];
    // state: L0 reads hA(i-1) from hA[pb]; L1 reads hB(i-2) from hB[pa]
    const short* stH = layer ? hBH[pa] : hAH[pb];
    const short* stL = layer ? hBL[pa] : hAL[pb];

    if (tid < 256) xnext = (i < T_STEPS - 1) ? xptr[i + 1] : 0.f;

    const bf16x8 IH0 = *(const bf16x8*)&inH[ra0], IH1 = *(const bf16x8*)&inH[ra1];
    const bf16x8 IL0 = *(const bf16x8*)&inL[ra0], IL1 = *(const bf16x8*)&inL[ra1];
    const bf16x8 SH0 = *(const bf16x8*)&stH[ra0], SH1 = *(const bf16x8*)&stH[ra1];
    const bf16x8 SL0 = *(const bf16x8*)&stL[ra0], SL1 = *(const bf16x8*)&stL[ra1];

    f32x4 aR = {0,0,0,0}, aZ = {0,0,0,0}, aI = {0,0,0,0}, aH = {0,0,0,0};
    GATE6(aR, SH0, SH1, SL0, SL1, whr);
    GATE6(aZ, SH0, SH1, SL0, SL1, whz);
    GATE6(aH, SH0, SH1, SL0, SL1, whn);
    GATE6(aR, IH0, IH1, IL0, IL1, wir);
    GATE6(aZ, IH0, IH1, IL0, IL1, wiz);
    GATE6(aI, IH0, IH1, IL0, IL1, win);

    {
      const float r = sigm(aR[0] + b_r);
      const float z = sigm(aZ[0] + b_z);
      const float n = tanh_fast((aI[0] + b_i) + r * (aH[0] + b_h));
      const float hnew = n + z * (hp - n);
      if (layer == 0) {
        hp = hnew;                       // hA(i)
        short h, l; split1(hp, &h, &l);
        hAH[pa][hwr] = h; hAL[pa][hwr] = l;
      } else if (i > 0) {
        hp = hnew;                       // hB(i-1)
        short h, l; split1(hp, &h, &l);
        hBH[pb][hwr] = h; hBL[pb][hwr] = l;
      }
    }
    if (tid < 256) {                     // stage x(i+1) into xs[pb]
      short h, l; split1(xnext, &h, &l);
      xsH[pb][xwr] = h; xsL[pb][xwr] = l;
    }
    __syncthreads();
  }

  if (layer == 1) hfin[quad * 64 + jg] = hp;   // hB(T-1)
  __syncthreads();

  // ---- classifier ----
  if (tid < 128) {
    const int bb = tid >> 5, u = tid & 31;
    float acc = b1[u];
    const float* w1r = W1 + u * HID;
    #pragma unroll
    for (int k = 0; k < 64; ++k)
      acc = fmaf(w1r[k], hfin[bb * 64 + k], acc);
    msf[(bb << 5) + u] = fmaxf(acc, 0.f);
  }
  __syncthreads();
  if (tid < 16) {
    const int bb = tid >> 2, c = tid & 3;
    float acc = b2[c];
    const float* w2r = W2 + (c << 5);
    #pragma unroll
    for (int u = 0; u < 32; ++u)
      acc = fmaf(w2r[u], msf[(bb << 5) + u], acc);
    out[(size_t)(b0 + bb) * 4 + c] = acc;
  }
}

extern "C" void kernel_launch(void* const* d_in, const int* in_sizes, int n_in,
                              void* d_out, int out_size, void* d_ws, size_t ws_size,
                              hipStream_t stream) {
  const float* x    = (const float*)d_in[0];
  const float* Wih0 = (const float*)d_in[1];
  const float* Whh0 = (const float*)d_in[2];
  const float* bih0 = (const float*)d_in[3];
  const float* bhh0 = (const float*)d_in[4];
  const float* Wih1 = (const float*)d_in[5];
  const float* Whh1 = (const float*)d_in[6];
  const float* bih1 = (const float*)d_in[7];
  const float* bhh1 = (const float*)d_in[8];
  const float* W1   = (const float*)d_in[9];
  const float* b1   = (const float*)d_in[10];
  const float* W2   = (const float*)d_in[11];
  const float* b2   = (const float*)d_in[12];
  float* out = (float*)d_out;

  hipLaunchKernelGGL(gru_mfma, dim3(256), dim3(512), 0, stream,
                     x, Wih0, Whh0, bih0, bhh0, Wih1, Whh1, bih1, bhh1,
                     W1, b1, W2, b2, out);
}